// Round 5
// baseline (355.756 us; speedup 1.0000x reference)
//
#include <hip/hip_runtime.h>
#include <stdint.h>

#define B_    4
#define CIN   32
#define NN    1024
#define SS    32
#define COUT  64
#define CSP   64
#define EPSV  1e-5f

// ---------- graph prep ----------
__global__ void detect_kernel(const int* __restrict__ ei, int* __restrict__ flag) {
    if (threadIdx.x == 0) {
        int nz = 0;
        for (int i = 1; i < 257; i += 2) nz |= ei[i];
        *flag = (nz == 0) ? 1 : 0;   // 1 => int64 layout
    }
}

__global__ void deg_count_kernel(const int* __restrict__ ei, int E,
                                 const int* __restrict__ flag, int* __restrict__ deg) {
    int e = blockIdx.x * 256 + threadIdx.x;
    int i64 = *flag;
    if (e < E) {
        int d = i64 ? ei[2 * (E + e)] : ei[E + e];
        atomicAdd(&deg[d], 1);
    }
}

__global__ __launch_bounds__(1024) void scan_kernel(
    const int* __restrict__ deg, int* __restrict__ row_ptr, float* __restrict__ dinv) {
    __shared__ int sb[NN];
    int t = threadIdx.x;
    int v = deg[t];
    sb[t] = v;
    __syncthreads();
    for (int off = 1; off < NN; off <<= 1) {
        int tmp = (t >= off) ? sb[t - off] : 0;
        __syncthreads();
        sb[t] += tmp;
        __syncthreads();
    }
    row_ptr[t] = sb[t] - v;                 // exclusive scan
    if (t == NN - 1) row_ptr[NN] = sb[t];
    dinv[t] = rsqrtf((float)(v + 1));       // +1 self-loop
}

// Packed edge descriptors: {srcn*64 (row offset in hw slice), dinv[srcn]}
__global__ void csr_fill_kernel(const int* __restrict__ ei, int E,
                                const int* __restrict__ flag,
                                const int* __restrict__ row_ptr, int* __restrict__ cursor,
                                const float* __restrict__ dinv, int2* __restrict__ edata) {
    int e = blockIdx.x * 256 + threadIdx.x;
    int i64 = *flag;
    if (e < E) {
        int s = i64 ? ei[2 * e] : ei[e];
        int d = i64 ? ei[2 * (E + e)] : ei[E + e];
        int pos = atomicAdd(&cursor[d], 1);
        edata[row_ptr[d] + pos] = make_int2(s * CSP, __float_as_int(dinv[s]));
    }
}

// ---------- temporal conv1 (4 tiles/block, grid 1024) + BN1 partial stats ----------
__global__ __launch_bounds__(256) void conv1_kernel(
    const float* __restrict__ x, const float* __restrict__ W1,
    const float* __restrict__ b1, float* __restrict__ h_pre,
    float* __restrict__ psum, float* __restrict__ pss) {
    __shared__ __align__(16) float xs[CIN][36];     // halo at [0] and [33]
    __shared__ float w1l[COUT * 97];
    int t = threadIdx.x;
    int grp = blockIdx.x;                           // 1024 groups of 4 n's
    int b = grp >> 8, n0 = (grp & 255) * 4;
#pragma unroll
    for (int i = 0; i < 6; i++) {
        int lin = (i * 256 + t) * 4;                // rows of 96 (96%4==0)
        int cout = lin / 96, r = lin - cout * 96;
        float4 v = *(const float4*)(W1 + lin);
        float* dst = &w1l[cout * 97 + r];
        dst[0] = v.x; dst[1] = v.y; dst[2] = v.z; dst[3] = v.w;
    }
    if (t < 64) xs[t & 31][(t < 32) ? 0 : 33] = 0.f;
    int cout = t >> 2, s0 = (t & 3) * 8;
    float bb = b1[cout];
    const float* wrow = &w1l[cout * 97];
    int sst = t & 31, cinb = t >> 5;                // staging: bank=(4*(t>>5)+(t&31))%32, 2-way
    float accS = 0.f, accQ = 0.f;
    for (int g = 0; g < 4; g++) {
        int n = n0 + g;
        __syncthreads();
#pragma unroll
        for (int i = 0; i < 4; i++) {
            int cin = cinb + 8 * i;
            xs[cin][sst + 1] = x[(((size_t)b * CIN + cin) * NN + n) * SS + sst];
        }
        __syncthreads();
        float y[8];
#pragma unroll
        for (int j = 0; j < 8; j++) y[j] = bb;
#pragma unroll 4
        for (int cin = 0; cin < CIN; cin++) {
            float w0 = wrow[cin * 3], w1v = wrow[cin * 3 + 1], w2v = wrow[cin * 3 + 2];
            const float* xr = &xs[cin][0];
            float4 xa = *(const float4*)(xr + s0);
            float4 xb = *(const float4*)(xr + s0 + 4);
            float4 xc = *(const float4*)(xr + s0 + 8);
            float xv[12] = {xa.x, xa.y, xa.z, xa.w, xb.x, xb.y, xb.z, xb.w,
                            xc.x, xc.y, xc.z, xc.w};
#pragma unroll
            for (int j = 0; j < 8; j++) y[j] += xv[j] * w0 + xv[j + 1] * w1v + xv[j + 2] * w2v;
        }
        float* op = h_pre + (size_t)(b * NN + n) * COUT * SS + cout * SS + s0;
        float4 o0 = {y[0], y[1], y[2], y[3]}, o1 = {y[4], y[5], y[6], y[7]};
        *(float4*)op = o0; *(float4*)(op + 4) = o1;
        float s = 0.f, q = 0.f;
#pragma unroll
        for (int j = 0; j < 8; j++) { s += y[j]; q += y[j] * y[j]; }
        s += __shfl_down(s, 1); s += __shfl_down(s, 2);
        q += __shfl_down(q, 1); q += __shfl_down(q, 2);
        accS += s; accQ += q;                       // valid on lanes (t&3)==0
    }
    if ((t & 3) == 0) {
        psum[cout * 1024 + grp] = accS;
        pss[cout * 1024 + grp] = accQ;
    }
}

// ---------- reduce per-block partials -> scale/shift (nslots = valid slots/ch) ----------
__global__ void bn_reduce_kernel(const float* __restrict__ psum, const float* __restrict__ pss,
                                 const float* __restrict__ g, const float* __restrict__ be,
                                 float* __restrict__ scale, float* __restrict__ shift,
                                 float invM, int stride, int nslots) {
    int c = blockIdx.x, t = threadIdx.x;    // 64 blocks x 256 threads
    const float* ps = psum + c * stride;
    const float* pq = pss + c * stride;
    float s = 0.f, q = 0.f;
    for (int i = t; i < nslots; i += 256) { s += ps[i]; q += pq[i]; }
#pragma unroll
    for (int o = 32; o > 0; o >>= 1) { s += __shfl_down(s, o); q += __shfl_down(q, o); }
    __shared__ float ws_[4], wq_[4];
    if ((t & 63) == 0) { ws_[t >> 6] = s; wq_[t >> 6] = q; }
    __syncthreads();
    if (t == 0) {
        float S = ws_[0] + ws_[1] + ws_[2] + ws_[3];
        float Q = wq_[0] + wq_[1] + wq_[2] + wq_[3];
        float m = S * invM, v = Q * invM - m * m;
        float sc = g[c] * rsqrtf(v + EPSV);
        scale[c] = sc;
        shift[c] = be[c] - m * sc;
    }
}

// ---------- BN1 apply + ReLU + (h · Wg) -> hw[B,S,N,Csp], 4 tiles/block ----------
__global__ __launch_bounds__(256) void bn1_gemm_kernel(
    const float* __restrict__ h_pre, const float* __restrict__ scale1,
    const float* __restrict__ shift1, const float* __restrict__ Wg,
    float* __restrict__ hw) {
    __shared__ __align__(16) float hs[COUT][36];
    __shared__ float wgl[COUT * CSP];
    int t = threadIdx.x;
    int grp = blockIdx.x;
    int b = grp >> 8, n0 = (grp & 255) * 4;
#pragma unroll
    for (int i = 0; i < 4; i++) {
        int lin = (i * 256 + t) * 4;
        float4 v = *(const float4*)(Wg + lin);
        wgl[lin] = v.x; wgl[lin + 1] = v.y; wgl[lin + 2] = v.z; wgl[lin + 3] = v.w;
    }
    int d = t & 63, sO = (t >> 6) * 8;      // compute role (sO wave-uniform)
    for (int g = 0; g < 4; g++) {
        int n = n0 + g;
        __syncthreads();
        const float* p = h_pre + (size_t)(b * NN + n) * COUT * SS;
#pragma unroll
        for (int i = 0; i < 8; i++) {
            int e = i * 256 + t;            // co=8i+(t>>5): bank=(4*(t>>5)+(t&31))%32, 2-way
            int co = e >> 5, s = e & 31;
            float v = p[e];
            hs[co][s] = fmaxf(scale1[co] * v + shift1[co], 0.f);
        }
        __syncthreads();
        float acc[8];
#pragma unroll
        for (int j = 0; j < 8; j++) acc[j] = 0.f;
#pragma unroll 4
        for (int c = 0; c < COUT; c++) {
            float w = wgl[c * 64 + d];
            float4 ha = *(const float4*)&hs[c][sO];
            float4 hb = *(const float4*)&hs[c][sO + 4];
            acc[0] += ha.x * w; acc[1] += ha.y * w; acc[2] += ha.z * w; acc[3] += ha.w * w;
            acc[4] += hb.x * w; acc[5] += hb.y * w; acc[6] += hb.z * w; acc[7] += hb.w * w;
        }
#pragma unroll
        for (int j = 0; j < 8; j++) {
            hw[((size_t)(b * SS + sO + j) * NN + n) * CSP + d] = acc[j];
        }
    }
}

// ---------- GCN aggregate (CSR gather, XCD-swizzled) + BN2 partial stats ----------
__global__ __launch_bounds__(256) void gcn_kernel(
    const float* __restrict__ hw, const int* __restrict__ row_ptr,
    const int2* __restrict__ edata, const float* __restrict__ dinv,
    const float* __restrict__ bg, float* __restrict__ agg,
    float* __restrict__ sum2, float* __restrict__ ss2) {
    int xcd = blockIdx.x & 7, j = blockIdx.x >> 3;
    int bs = xcd * 16 + (j >> 5), ng = j & 31;
    int d = threadIdx.x & 63, nl = threadIdx.x >> 6;
    const float* hwb = hw + (size_t)bs * NN * CSP;
    float* aggb = agg + (size_t)bs * NN * CSP;
    float bgf = bg[d];
    float sum = 0.f, ss = 0.f;
    for (int i = 0; i < 8; i++) {
        int n = ng * 32 + i * 4 + nl;                   // wave-uniform n
        int r0 = row_ptr[n], r1 = row_ptr[n + 1];
        float dn = dinv[n];
        float a0 = dn * hwb[n * CSP + d];               // self-loop
        float a1 = 0.f, a2 = 0.f, a3 = 0.f;
        int r = r0;
        for (; r + 4 <= r1; r += 4) {                   // 4 independent chains
            int2 e0 = edata[r], e1 = edata[r + 1], e2 = edata[r + 2], e3 = edata[r + 3];
            a0 += __int_as_float(e0.y) * hwb[e0.x + d];
            a1 += __int_as_float(e1.y) * hwb[e1.x + d];
            a2 += __int_as_float(e2.y) * hwb[e2.x + d];
            a3 += __int_as_float(e3.y) * hwb[e3.x + d];
        }
        for (; r < r1; r++) {
            int2 e = edata[r];
            a0 += __int_as_float(e.y) * hwb[e.x + d];
        }
        float v = dn * ((a0 + a1) + (a2 + a3)) + bgf;
        aggb[n * CSP + d] = v;
        sum += v; ss += v * v;
    }
    __shared__ float ls[4][64], lq[4][64];
    ls[nl][d] = sum; lq[nl][d] = ss;
    __syncthreads();
    if (threadIdx.x < 64) {
        float s = ls[0][d] + ls[1][d] + ls[2][d] + ls[3][d];
        float q = lq[0][d] + lq[1][d] + lq[2][d] + lq[3][d];
        atomicAdd(&sum2[bs * 64 + d], s);
        atomicAdd(&ss2[bs * 64 + d], q);
    }
}

__global__ void bn2_finalize_kernel(const float* __restrict__ sum2, const float* __restrict__ ss2,
                                    const float* __restrict__ gs, const float* __restrict__ bes,
                                    float* __restrict__ scale2, float* __restrict__ shift2) {
    int idx = blockIdx.x * 256 + threadIdx.x;   // 8192 = B*S*Csp
    int d = idx & 63;
    float m = sum2[idx] * (1.f / NN);
    float v = ss2[idx] * (1.f / NN) - m * m;
    float sc = gs[d] * rsqrtf(v + EPSV);
    scale2[idx] = sc;
    shift2[idx] = bes[d] - m * sc;
}

// ---------- BN2 apply + ReLU + conv2 (cout-split, 8 tiles/block) + BN3 partials ----------
__global__ __launch_bounds__(256) void conv2_kernel(
    const float* __restrict__ agg, const float* __restrict__ scale2,
    const float* __restrict__ shift2, const float* __restrict__ W2,
    const float* __restrict__ b2, float* __restrict__ h2_pre,
    float* __restrict__ psum, float* __restrict__ pss) {
    __shared__ __align__(16) float ts[CSP][36];     // halo at [0] and [33]
    __shared__ float w2l[32 * 193];                 // half the couts: 24.7 KB
    int t = threadIdx.x;
    int grp = blockIdx.x;                           // 1024 = b(4) x ngrp(128) x chalf(2)
    int chalf = grp & 1, ngrp = (grp >> 1) & 127, b = grp >> 8;
    int n0 = ngrp * 8;
#pragma unroll
    for (int i = 0; i < 6; i++) {
        int lin = (i * 256 + t) * 4;                // 6144 floats, rows of 192
        int cl = lin / 192, r = lin - cl * 192;
        float4 v = *(const float4*)(W2 + chalf * 6144 + lin);
        float* dst = &w2l[cl * 193 + r];
        dst[0] = v.x; dst[1] = v.y; dst[2] = v.z; dst[3] = v.w;
    }
    if (t < 128) ts[t & 63][(t < 64) ? 0 : 33] = 0.f;
    int cl = t >> 3, s0 = (t & 7) * 4;
    int cout_g = chalf * 32 + cl;
    float bb = b2[cout_g];
    const float* wrow = &w2l[cl * 193];
    int scin = t >> 2, ssl = t & 3;                 // staging: bank 2-way
    float accS = 0.f, accQ = 0.f;
    for (int g = 0; g < 8; g++) {
        int n = n0 + g;
        __syncthreads();
#pragma unroll
        for (int i = 0; i < 8; i++) {
            int s = i * 4 + ssl;
            int bsi = b * SS + s;
            float v = agg[((size_t)bsi * NN + n) * CSP + scin];
            v = fmaxf(scale2[bsi * 64 + scin] * v + shift2[bsi * 64 + scin], 0.f);
            ts[scin][s + 1] = v;
        }
        __syncthreads();
        float y[4] = {bb, bb, bb, bb};
#pragma unroll 4
        for (int cin = 0; cin < CSP; cin++) {
            float w0 = wrow[cin * 3], w1v = wrow[cin * 3 + 1], w2v = wrow[cin * 3 + 2];
            const float* xr = &ts[cin][0];
            float4 xa = *(const float4*)(xr + s0);
            float2 xb = *(const float2*)(xr + s0 + 4);
            float xv[6] = {xa.x, xa.y, xa.z, xa.w, xb.x, xb.y};
            y[0] += xv[0] * w0 + xv[1] * w1v + xv[2] * w2v;
            y[1] += xv[1] * w0 + xv[2] * w1v + xv[3] * w2v;
            y[2] += xv[2] * w0 + xv[3] * w1v + xv[4] * w2v;
            y[3] += xv[3] * w0 + xv[4] * w1v + xv[5] * w2v;
        }
        float* op = h2_pre + (size_t)(b * NN + n) * COUT * SS + cout_g * SS + s0;
        float4 o0 = {y[0], y[1], y[2], y[3]};
        *(float4*)op = o0;
        float s = y[0] + y[1] + y[2] + y[3];
        float q = y[0] * y[0] + y[1] * y[1] + y[2] * y[2] + y[3] * y[3];
        s += __shfl_down(s, 1); s += __shfl_down(s, 2); s += __shfl_down(s, 4);
        q += __shfl_down(q, 1); q += __shfl_down(q, 2); q += __shfl_down(q, 4);
        accS += s; accQ += q;                       // valid on lanes (t&7)==0
    }
    // FIX: compact dense slot index (grp>>1 uniquely ids (b, ngrp)); round-3 version
    // left half the 1024-slot range holding conv1's stale partials.
    if ((t & 7) == 0) {
        psum[cout_g * 1024 + (grp >> 1)] = accS;
        pss[cout_g * 1024 + (grp >> 1)] = accQ;
    }
}

// ---------- final: BN3+ReLU + residual 1x1 conv + ReLU, write [B,Cout,N,S] ----------
__global__ __launch_bounds__(256) void final_kernel(
    const float* __restrict__ x, const float* __restrict__ Wres,
    const float* __restrict__ bres, const float* __restrict__ h2_pre,
    const float* __restrict__ scale3, const float* __restrict__ shift3,
    float* __restrict__ out) {
    __shared__ __align__(16) float xs[CIN][36];
    __shared__ float wrl[COUT * 33];
    int t = threadIdx.x;
    int bn = blockIdx.x;
    int b = bn >> 10, n = bn & (NN - 1);
    {
        int sst = t & 31, cinb = t >> 5;            // bank 2-way
#pragma unroll
        for (int i = 0; i < 4; i++) {
            int cin = cinb + 8 * i;
            xs[cin][sst] = x[(((size_t)b * CIN + cin) * NN + n) * SS + sst];
        }
    }
#pragma unroll
    for (int i = 0; i < 2; i++) {
        int lin = (i * 256 + t) * 4;                // rows of 32
        int cw = lin >> 5, c0 = lin & 31;
        float4 v = *(const float4*)(Wres + lin);
        float* dst = &wrl[cw * 33 + c0];
        dst[0] = v.x; dst[1] = v.y; dst[2] = v.z; dst[3] = v.w;
    }
    __syncthreads();
    int cout = t >> 2, s0 = (t & 3) * 8;
    float res[8];
    float bb = bres[cout];
#pragma unroll
    for (int j = 0; j < 8; j++) res[j] = bb;
    const float* wrow = &wrl[cout * 33];
#pragma unroll 4
    for (int cin = 0; cin < CIN; cin++) {
        float w = wrow[cin];
        float4 xa = *(const float4*)&xs[cin][s0];
        float4 xb = *(const float4*)&xs[cin][s0 + 4];
        res[0] += xa.x * w; res[1] += xa.y * w; res[2] += xa.z * w; res[3] += xa.w * w;
        res[4] += xb.x * w; res[5] += xb.y * w; res[6] += xb.z * w; res[7] += xb.w * w;
    }
    const float* hp = h2_pre + (size_t)bn * COUT * SS + cout * SS + s0;
    float4 h0 = *(const float4*)hp, h1 = *(const float4*)(hp + 4);
    float h2[8] = {h0.x, h0.y, h0.z, h0.w, h1.x, h1.y, h1.z, h1.w};
    float sc = scale3[cout], sh = shift3[cout];
    float o[8];
#pragma unroll
    for (int j = 0; j < 8; j++) {
        float hv = fmaxf(sc * h2[j] + sh, 0.f);
        o[j] = fmaxf(hv + res[j], 0.f);
    }
    float* op = out + (((size_t)b * COUT + cout) * NN + n) * SS + s0;
    float4 o0 = {o[0], o[1], o[2], o[3]}, o1 = {o[4], o[5], o[6], o[7]};
    *(float4*)op = o0; *(float4*)(op + 4) = o1;
}

// ---------- host ----------
extern "C" void kernel_launch(void* const* d_in, const int* in_sizes, int n_in,
                              void* d_out, int out_size, void* d_ws, size_t ws_size,
                              hipStream_t stream) {
    const float* x    = (const float*)d_in[0];
    const int*   ei   = (const int*)  d_in[1];
    const float* W1   = (const float*)d_in[2];
    const float* b1   = (const float*)d_in[3];
    const float* g1   = (const float*)d_in[4];
    const float* be1  = (const float*)d_in[5];
    const float* Wg   = (const float*)d_in[6];
    const float* bg   = (const float*)d_in[7];
    const float* gs   = (const float*)d_in[8];
    const float* bes  = (const float*)d_in[9];
    const float* W2   = (const float*)d_in[10];
    const float* b2   = (const float*)d_in[11];
    const float* g2   = (const float*)d_in[12];
    const float* be2  = (const float*)d_in[13];
    const float* Wres = (const float*)d_in[14];
    const float* bres = (const float*)d_in[15];
    float* out = (float*)d_out;
    int E = in_sizes[1] / 2;

    char* ws = (char*)d_ws;
    // zeroed region: [0, 73728)
    int*   deg    = (int*)  (ws + 0);            // 4096 B
    int*   cursor = (int*)  (ws + 4096);         // 4096 B
    float* sum2   = (float*)(ws + 8192);         // 32768 B
    float* ssq2   = (float*)(ws + 40960);        // 32768 B -> ends 73728
    int*   row_ptr= (int*)  (ws + 73728);        // 4100 B
    int*   flag   = (int*)  (ws + 77888);        // 4 B
    float* dinv   = (float*)(ws + 78080);        // 4096 B
    float* scale1 = (float*)(ws + 82176);        // 256 B each
    float* shift1 = (float*)(ws + 82432);
    float* scale3 = (float*)(ws + 82688);
    float* shift3 = (float*)(ws + 82944);
    float* scale2 = (float*)(ws + 83200);        // 32768 B
    float* shift2 = (float*)(ws + 115968);       // 32768 B -> 148736
    float* psum   = (float*)(ws + 148736);       // 262144 B (64 ch x 1024 slots)
    float* pss    = (float*)(ws + 410880);       // 262144 B -> 673024
    int2*  edata  = (int2*) (ws + 673024);       // 8*E = 131072 B -> 804096
    float* bigA   = (float*)(ws + 804352);       // 33.55 MB: hw, then h2_pre
    // d_out doubles as scratch: h_pre (conv1 out), then agg (gcn out).
    float* h_pre  = out;
    float* agg    = out;

    hipMemsetAsync(ws, 0, 73728, stream);
    detect_kernel<<<1, 64, 0, stream>>>(ei, flag);
    int egrid = (E + 255) / 256;
    deg_count_kernel<<<egrid, 256, 0, stream>>>(ei, E, flag, deg);
    scan_kernel<<<1, NN, 0, stream>>>(deg, row_ptr, dinv);
    csr_fill_kernel<<<egrid, 256, 0, stream>>>(ei, E, flag, row_ptr, cursor, dinv, edata);

    conv1_kernel<<<1024, 256, 0, stream>>>(x, W1, b1, h_pre, psum, pss);
    bn_reduce_kernel<<<64, 256, 0, stream>>>(psum, pss, g1, be1, scale1, shift1,
                                             1.f / (B_ * NN * SS), 1024, 1024);
    bn1_gemm_kernel<<<1024, 256, 0, stream>>>(h_pre, scale1, shift1, Wg, bigA);
    gcn_kernel<<<B_ * SS * (NN / 32), 256, 0, stream>>>(bigA, row_ptr, edata, dinv, bg, agg,
                                                        sum2, ssq2);
    bn2_finalize_kernel<<<32, 256, 0, stream>>>(sum2, ssq2, gs, bes, scale2, shift2);
    conv2_kernel<<<1024, 256, 0, stream>>>(agg, scale2, shift2, W2, b2, bigA, psum, pss);
    bn_reduce_kernel<<<64, 256, 0, stream>>>(psum, pss, g2, be2, scale3, shift3,
                                             1.f / (B_ * NN * SS), 1024, 512);
    final_kernel<<<B_ * NN, 256, 0, stream>>>(x, Wres, bres, bigA, scale3, shift3, out);
}

// Round 6
// 299.863 us; speedup vs baseline: 1.1864x; 1.1864x over previous
//
#include <hip/hip_runtime.h>
#include <stdint.h>

#define B_    4
#define CIN   32
#define NN    1024
#define SS    32
#define COUT  64
#define CSP   64
#define EPSV  1e-5f

// ---------- graph prep ----------
__global__ void detect_kernel(const int* __restrict__ ei, int* __restrict__ flag) {
    if (threadIdx.x == 0) {
        int nz = 0;
        for (int i = 1; i < 257; i += 2) nz |= ei[i];
        *flag = (nz == 0) ? 1 : 0;   // 1 => int64 layout
    }
}

__global__ void deg_count_kernel(const int* __restrict__ ei, int E,
                                 const int* __restrict__ flag, int* __restrict__ deg) {
    int e = blockIdx.x * 256 + threadIdx.x;
    int i64 = *flag;
    if (e < E) {
        int d = i64 ? ei[2 * (E + e)] : ei[E + e];
        atomicAdd(&deg[d], 1);
    }
}

__global__ __launch_bounds__(1024) void scan_kernel(
    const int* __restrict__ deg, int* __restrict__ row_ptr, float* __restrict__ dinv) {
    __shared__ int sb[NN];
    int t = threadIdx.x;
    int v = deg[t];
    sb[t] = v;
    __syncthreads();
    for (int off = 1; off < NN; off <<= 1) {
        int tmp = (t >= off) ? sb[t - off] : 0;
        __syncthreads();
        sb[t] += tmp;
        __syncthreads();
    }
    row_ptr[t] = sb[t] - v;                 // exclusive scan
    if (t == NN - 1) row_ptr[NN] = sb[t];
    dinv[t] = rsqrtf((float)(v + 1));       // +1 self-loop
}

__global__ void csr_fill_kernel(const int* __restrict__ ei, int E,
                                const int* __restrict__ flag,
                                const int* __restrict__ row_ptr, int* __restrict__ cursor,
                                const float* __restrict__ dinv, int2* __restrict__ edata) {
    int e = blockIdx.x * 256 + threadIdx.x;
    int i64 = *flag;
    if (e < E) {
        int s = i64 ? ei[2 * e] : ei[e];
        int d = i64 ? ei[2 * (E + e)] : ei[E + e];
        int pos = atomicAdd(&cursor[d], 1);
        edata[row_ptr[d] + pos] = make_int2(s * CSP, __float_as_int(dinv[s]));
    }
}

// ---------- temporal conv1: 8n/block, 4cout x 8s per thread, wave = n ----------
__global__ __launch_bounds__(512, 4) void conv1_kernel(
    const float* __restrict__ x, const float* __restrict__ W1,
    const float* __restrict__ b1, float* __restrict__ h_pre,
    float* __restrict__ psum, float* __restrict__ pss) {
    __shared__ __align__(16) float pool[15360];    // xs[32*288] | w1l[96*64] = 61.4 KB
    float* xs  = pool;                             // [cin][n*36 + s], halo 0 at [32],[35]
    float* w1l = pool + 9216;                      // [kk][cout] (transposed)
    int t = threadIdx.x;
    int grp = blockIdx.x;                          // 512 = b(4) x ngrp(128)
    int b = grp >> 7, n0 = (grp & 127) * 8;
    {   // W1[cout][96] -> w1l[kk][cout]
        int cout = t >> 3, kkb = (t & 7) * 12;
        const float* wsrc = W1 + cout * 96 + kkb;
#pragma unroll
        for (int j = 0; j < 12; j++) w1l[(kkb + j) * 64 + cout] = wsrc[j];
    }
    if (t < 256) {                                 // halo zeros (slots 32..35)
        float* p = xs + (t >> 3) * 288 + (t & 7) * 36 + 32;
        p[0] = 0.f; p[1] = 0.f; p[2] = 0.f; p[3] = 0.f;
    }
#pragma unroll
    for (int i = 0; i < 4; i++) {                  // stage x: 1 KB contiguous per wave
        int flat4 = i * 512 + t;
        int cin = flat4 >> 6;
        int rem = flat4 & 63;
        int n = rem >> 3, s4 = (rem & 7) * 4;
        float4 v = *(const float4*)(x + (((size_t)b * CIN + cin) * NN + n0 + n) * SS + s4);
        *(float4*)(xs + cin * 288 + n * 36 + s4) = v;
    }
    __syncthreads();
    int lane = t & 63, wvi = t >> 6;
    int n = wvi;                                   // one n per wave
    int cout0 = 4 * (lane & 15), s0 = 8 * ((lane >> 4) & 3);
    int m1 = (s0 == 0) ? 35 : (s0 - 1);            // left halo lives at [35]
    float y[4][8];
#pragma unroll
    for (int cc = 0; cc < 4; cc++) {
        float bbv = b1[cout0 + cc];
#pragma unroll
        for (int j = 0; j < 8; j++) y[cc][j] = bbv;
    }
#pragma unroll 4
    for (int cin = 0; cin < CIN; cin++) {
        const float* xr = xs + cin * 288 + n * 36;
        float xw[10];
        xw[0] = xr[m1];
        float4 xa = *(const float4*)(xr + s0);
        float4 xb = *(const float4*)(xr + s0 + 4);
        xw[1] = xa.x; xw[2] = xa.y; xw[3] = xa.z; xw[4] = xa.w;
        xw[5] = xb.x; xw[6] = xb.y; xw[7] = xb.z; xw[8] = xb.w;
        xw[9] = xr[s0 + 8];
        const float* wb = w1l + (3 * cin) * 64 + cout0;
        float4 w0 = *(const float4*)(wb);
        float4 w1v = *(const float4*)(wb + 64);
        float4 w2v = *(const float4*)(wb + 128);
        float wk0[4] = {w0.x, w0.y, w0.z, w0.w};
        float wk1[4] = {w1v.x, w1v.y, w1v.z, w1v.w};
        float wk2[4] = {w2v.x, w2v.y, w2v.z, w2v.w};
#pragma unroll
        for (int cc = 0; cc < 4; cc++)
#pragma unroll
            for (int j = 0; j < 8; j++)
                y[cc][j] += wk0[cc] * xw[j] + wk1[cc] * xw[j + 1] + wk2[cc] * xw[j + 2];
    }
    float* hb = h_pre + (((size_t)(b * NN + n0 + n)) * COUT + cout0) * SS + s0;
#pragma unroll
    for (int cc = 0; cc < 4; cc++) {
        float4 o0 = {y[cc][0], y[cc][1], y[cc][2], y[cc][3]};
        float4 o1 = {y[cc][4], y[cc][5], y[cc][6], y[cc][7]};
        *(float4*)(hb + cc * SS) = o0;
        *(float4*)(hb + cc * SS + 4) = o1;
    }
    float aS[4], aQ[4];
#pragma unroll
    for (int cc = 0; cc < 4; cc++) {
        float s_ = 0.f, q_ = 0.f;
#pragma unroll
        for (int j = 0; j < 8; j++) { s_ += y[cc][j]; q_ += y[cc][j] * y[cc][j]; }
        s_ += __shfl_down(s_, 16); s_ += __shfl_down(s_, 32);
        q_ += __shfl_down(q_, 16); q_ += __shfl_down(q_, 32);
        aS[cc] = s_; aQ[cc] = q_;
    }
    __syncthreads();                               // xs dead -> reuse pool as red
    float* redS = pool;
    float* redQ = pool + 512;
    if (lane < 16) {
#pragma unroll
        for (int cc = 0; cc < 4; cc++) {
            redS[wvi * 64 + 4 * lane + cc] = aS[cc];
            redQ[wvi * 64 + 4 * lane + cc] = aQ[cc];
        }
    }
    __syncthreads();
    if (t < 64) {
        float S = 0.f, Q = 0.f;
#pragma unroll
        for (int w = 0; w < 8; w++) { S += redS[w * 64 + t]; Q += redQ[w * 64 + t]; }
        psum[t * 512 + grp] = S;
        pss[t * 512 + grp] = Q;
    }
}

// ---------- reduce per-block partials -> scale/shift ----------
__global__ void bn_reduce_kernel(const float* __restrict__ psum, const float* __restrict__ pss,
                                 const float* __restrict__ g, const float* __restrict__ be,
                                 float* __restrict__ scale, float* __restrict__ shift,
                                 float invM, int stride, int nslots) {
    int c = blockIdx.x, t = threadIdx.x;    // 64 blocks x 256 threads
    const float* ps = psum + c * stride;
    const float* pq = pss + c * stride;
    float s = 0.f, q = 0.f;
    for (int i = t; i < nslots; i += 256) { s += ps[i]; q += pq[i]; }
#pragma unroll
    for (int o = 32; o > 0; o >>= 1) { s += __shfl_down(s, o); q += __shfl_down(q, o); }
    __shared__ float ws_[4], wq_[4];
    if ((t & 63) == 0) { ws_[t >> 6] = s; wq_[t >> 6] = q; }
    __syncthreads();
    if (t == 0) {
        float S = ws_[0] + ws_[1] + ws_[2] + ws_[3];
        float Q = wq_[0] + wq_[1] + wq_[2] + wq_[3];
        float m = S * invM, v = Q * invM - m * m;
        float sc = g[c] * rsqrtf(v + EPSV);
        scale[c] = sc;
        shift[c] = be[c] - m * sc;
    }
}

// ---------- BN1 apply + ReLU + (h · Wg) -> hw[B,S,N,Csp]; 4n/block, wave = n ----------
__global__ __launch_bounds__(256, 2) void bn1_gemm_kernel(
    const float* __restrict__ h_pre, const float* __restrict__ scale1,
    const float* __restrict__ shift1, const float* __restrict__ Wg,
    float* __restrict__ hw) {
    __shared__ __align__(16) float hs[COUT * 144];  // [c][n*36+s], 36.9 KB
    __shared__ __align__(16) float wgl[COUT * CSP]; // 16.4 KB
    int t = threadIdx.x;
    int grp = blockIdx.x;                           // 1024 = b(4) x 256
    int b = grp >> 8, n0 = (grp & 255) * 4;
#pragma unroll
    for (int i = 0; i < 4; i++)
        ((float4*)wgl)[i * 256 + t] = ((const float4*)Wg)[i * 256 + t];
#pragma unroll
    for (int i = 0; i < 8; i++) {
        int flat4 = i * 256 + t;
        int n = flat4 >> 9;
        int rem = flat4 & 511;
        int c = rem >> 3, s4 = (rem & 7) * 4;
        float sc1 = scale1[c], sh1 = shift1[c];
        const float* p = h_pre + (((size_t)(b * NN + n0 + n)) * COUT + c) * SS + s4;
        float4 u = *(const float4*)p;
        float4 v;
        v.x = fmaxf(u.x * sc1 + sh1, 0.f);
        v.y = fmaxf(u.y * sc1 + sh1, 0.f);
        v.z = fmaxf(u.z * sc1 + sh1, 0.f);
        v.w = fmaxf(u.w * sc1 + sh1, 0.f);
        *(float4*)(hs + c * 144 + n * 36 + s4) = v;
    }
    __syncthreads();
    int lane = t & 63, n = t >> 6;
    int d0 = 4 * (lane & 15), s0 = 8 * ((lane >> 4) & 3);
    float acc[4][8];
#pragma unroll
    for (int cc = 0; cc < 4; cc++)
#pragma unroll
        for (int j = 0; j < 8; j++) acc[cc][j] = 0.f;
#pragma unroll 4
    for (int c = 0; c < COUT; c++) {
        float4 w4 = *(const float4*)(wgl + c * 64 + d0);
        const float* xr = hs + c * 144 + n * 36;
        float4 xa = *(const float4*)(xr + s0);
        float4 xb = *(const float4*)(xr + s0 + 4);
        float xv[8] = {xa.x, xa.y, xa.z, xa.w, xb.x, xb.y, xb.z, xb.w};
#pragma unroll
        for (int j = 0; j < 8; j++) {
            acc[0][j] += xv[j] * w4.x;
            acc[1][j] += xv[j] * w4.y;
            acc[2][j] += xv[j] * w4.z;
            acc[3][j] += xv[j] * w4.w;
        }
    }
#pragma unroll
    for (int j = 0; j < 8; j++) {
        float4 o = {acc[0][j], acc[1][j], acc[2][j], acc[3][j]};
        *(float4*)(hw + (((size_t)(b * SS + s0 + j)) * NN + n0 + n) * CSP + d0) = o;
    }
}

// ---------- GCN aggregate (CSR gather, XCD-swizzled); writes agg[B,N,S,C] ----------
__global__ __launch_bounds__(256) void gcn_kernel(
    const float* __restrict__ hw, const int* __restrict__ row_ptr,
    const int2* __restrict__ edata, const float* __restrict__ dinv,
    const float* __restrict__ bg, float* __restrict__ agg,
    float* __restrict__ sum2, float* __restrict__ ss2) {
    int xcd = blockIdx.x & 7, j = blockIdx.x >> 3;
    int bs = xcd * 16 + (j >> 5), ng = j & 31;
    int bb2 = bs >> 5, ss2_ = bs & 31;
    int d = threadIdx.x & 63, nl = threadIdx.x >> 6;
    const float* hwb = hw + (size_t)bs * NN * CSP;
    float* aggb = agg + (((size_t)bb2 * NN) * SS + ss2_) * CSP;
    float bgf = bg[d];
    float sum = 0.f, ss = 0.f;
    for (int i = 0; i < 8; i++) {
        int n = ng * 32 + i * 4 + nl;                   // wave-uniform n
        int r0 = row_ptr[n], r1 = row_ptr[n + 1];
        float dn = dinv[n];
        float a0 = dn * hwb[n * CSP + d];               // self-loop
        float a1 = 0.f, a2 = 0.f, a3 = 0.f;
        int r = r0;
        for (; r + 4 <= r1; r += 4) {                   // 4 independent chains
            int2 e0 = edata[r], e1 = edata[r + 1], e2 = edata[r + 2], e3 = edata[r + 3];
            a0 += __int_as_float(e0.y) * hwb[e0.x + d];
            a1 += __int_as_float(e1.y) * hwb[e1.x + d];
            a2 += __int_as_float(e2.y) * hwb[e2.x + d];
            a3 += __int_as_float(e3.y) * hwb[e3.x + d];
        }
        for (; r < r1; r++) {
            int2 e = edata[r];
            a0 += __int_as_float(e.y) * hwb[e.x + d];
        }
        float v = dn * ((a0 + a1) + (a2 + a3)) + bgf;
        aggb[((size_t)n * SS) * CSP + d] = v;           // [B,N,S,C]
        sum += v; ss += v * v;
    }
    __shared__ float ls[4][64], lq[4][64];
    ls[nl][d] = sum; lq[nl][d] = ss;
    __syncthreads();
    if (threadIdx.x < 64) {
        float s = ls[0][d] + ls[1][d] + ls[2][d] + ls[3][d];
        float q = lq[0][d] + lq[1][d] + lq[2][d] + lq[3][d];
        atomicAdd(&sum2[bs * 64 + d], s);
        atomicAdd(&ss2[bs * 64 + d], q);
    }
}

__global__ void bn2_finalize_kernel(const float* __restrict__ sum2, const float* __restrict__ ss2,
                                    const float* __restrict__ gs, const float* __restrict__ bes,
                                    float* __restrict__ scale2, float* __restrict__ shift2) {
    int idx = blockIdx.x * 256 + threadIdx.x;   // 8192 = B*S*Csp
    int d = idx & 63;
    float m = sum2[idx] * (1.f / NN);
    float v = ss2[idx] * (1.f / NN) - m * m;
    float sc = gs[d] * rsqrtf(v + EPSV);
    scale2[idx] = sc;
    shift2[idx] = bes[d] - m * sc;
}

// ---------- BN2+ReLU + conv2: 8n/block, cin-halved LDS, reg accumulators ----------
__global__ __launch_bounds__(512, 4) void conv2_kernel(
    const float* __restrict__ agg, const float* __restrict__ scale2,
    const float* __restrict__ shift2, const float* __restrict__ W2,
    const float* __restrict__ b2, float* __restrict__ h2_pre,
    float* __restrict__ psum, float* __restrict__ pss) {
    __shared__ __align__(16) float pool[15360];    // ts[32*288] | w2l[96*64] = 61.4 KB
    float* ts  = pool;                             // [cinL][n*36+s]
    float* w2l = pool + 9216;                      // [kkL][cout]
    int t = threadIdx.x;
    int grp = blockIdx.x;                          // 512 = b(4) x ngrp(128)
    int b = grp >> 7, n0 = (grp & 127) * 8;
    int s_st = (t >> 3) & 31;                      // staging s (const per thread)
    int c4_st = t & 7;                             // staging c-quad
    if (t < 256) {                                 // halo zeros (persist across halves)
        float* p = ts + (t >> 3) * 288 + (t & 7) * 36 + 32;
        p[0] = 0.f; p[1] = 0.f; p[2] = 0.f; p[3] = 0.f;
    }
    int lane = t & 63, wvi = t >> 6;
    int n = wvi;
    int cout0 = 4 * (lane & 15), s0 = 8 * ((lane >> 4) & 3);
    int m1 = (s0 == 0) ? 35 : (s0 - 1);
    float y[4][8];
#pragma unroll
    for (int cc = 0; cc < 4; cc++) {
        float bbv = b2[cout0 + cc];
#pragma unroll
        for (int j = 0; j < 8; j++) y[cc][j] = bbv;
    }
    for (int half = 0; half < 2; half++) {
        __syncthreads();                           // prev compute done / halos published
        {   // stage weight half: kk in [half*96, half*96+96)
            int cout = t >> 3, kkb = (t & 7) * 12;
            const float* wsrc = W2 + cout * 192 + half * 96 + kkb;
#pragma unroll
            for (int j = 0; j < 12; j++) w2l[(kkb + j) * 64 + cout] = wsrc[j];
        }
        {   // stage activation half from agg[B,N,S,C] with BN2+ReLU
            int c0 = half * 32 + 4 * c4_st;
            int bsi = b * SS + s_st;
            float4 sc = *(const float4*)(scale2 + bsi * 64 + c0);
            float4 sh = *(const float4*)(shift2 + bsi * 64 + c0);
            int cL = 4 * c4_st;
#pragma unroll
            for (int i = 0; i < 4; i++) {
                int nn_ = 2 * i + (t >> 8);
                float4 u = *(const float4*)(agg +
                    (((size_t)(b * NN + n0 + nn_)) * SS + s_st) * CSP + c0);
                float* dst = ts + cL * 288 + nn_ * 36 + s_st;
                dst[0]   = fmaxf(u.x * sc.x + sh.x, 0.f);
                dst[288] = fmaxf(u.y * sc.y + sh.y, 0.f);
                dst[576] = fmaxf(u.z * sc.z + sh.z, 0.f);
                dst[864] = fmaxf(u.w * sc.w + sh.w, 0.f);
            }
        }
        __syncthreads();
#pragma unroll 4
        for (int cl = 0; cl < 32; cl++) {
            const float* xr = ts + cl * 288 + n * 36;
            float xw[10];
            xw[0] = xr[m1];
            float4 xa = *(const float4*)(xr + s0);
            float4 xb = *(const float4*)(xr + s0 + 4);
            xw[1] = xa.x; xw[2] = xa.y; xw[3] = xa.z; xw[4] = xa.w;
            xw[5] = xb.x; xw[6] = xb.y; xw[7] = xb.z; xw[8] = xb.w;
            xw[9] = xr[s0 + 8];
            const float* wb = w2l + (3 * cl) * 64 + cout0;
            float4 w0 = *(const float4*)(wb);
            float4 w1v = *(const float4*)(wb + 64);
            float4 w2v = *(const float4*)(wb + 128);
            float wk0[4] = {w0.x, w0.y, w0.z, w0.w};
            float wk1[4] = {w1v.x, w1v.y, w1v.z, w1v.w};
            float wk2[4] = {w2v.x, w2v.y, w2v.z, w2v.w};
#pragma unroll
            for (int cc = 0; cc < 4; cc++)
#pragma unroll
                for (int j = 0; j < 8; j++)
                    y[cc][j] += wk0[cc] * xw[j] + wk1[cc] * xw[j + 1] + wk2[cc] * xw[j + 2];
        }
    }
    float* hb = h2_pre + (((size_t)(b * NN + n0 + n)) * COUT + cout0) * SS + s0;
#pragma unroll
    for (int cc = 0; cc < 4; cc++) {
        float4 o0 = {y[cc][0], y[cc][1], y[cc][2], y[cc][3]};
        float4 o1 = {y[cc][4], y[cc][5], y[cc][6], y[cc][7]};
        *(float4*)(hb + cc * SS) = o0;
        *(float4*)(hb + cc * SS + 4) = o1;
    }
    float aS[4], aQ[4];
#pragma unroll
    for (int cc = 0; cc < 4; cc++) {
        float s_ = 0.f, q_ = 0.f;
#pragma unroll
        for (int j = 0; j < 8; j++) { s_ += y[cc][j]; q_ += y[cc][j] * y[cc][j]; }
        s_ += __shfl_down(s_, 16); s_ += __shfl_down(s_, 32);
        q_ += __shfl_down(q_, 16); q_ += __shfl_down(q_, 32);
        aS[cc] = s_; aQ[cc] = q_;
    }
    __syncthreads();                               // ts dead -> reuse pool
    float* redS = pool;
    float* redQ = pool + 512;
    if (lane < 16) {
#pragma unroll
        for (int cc = 0; cc < 4; cc++) {
            redS[wvi * 64 + 4 * lane + cc] = aS[cc];
            redQ[wvi * 64 + 4 * lane + cc] = aQ[cc];
        }
    }
    __syncthreads();
    if (t < 64) {
        float S = 0.f, Q = 0.f;
#pragma unroll
        for (int w = 0; w < 8; w++) { S += redS[w * 64 + t]; Q += redQ[w * 64 + t]; }
        psum[t * 512 + grp] = S;
        pss[t * 512 + grp] = Q;
    }
}

// ---------- final: BN3+ReLU + residual 1x1 conv + ReLU, write [B,Cout,N,S] ----------
__global__ __launch_bounds__(256) void final_kernel(
    const float* __restrict__ x, const float* __restrict__ Wres,
    const float* __restrict__ bres, const float* __restrict__ h2_pre,
    const float* __restrict__ scale3, const float* __restrict__ shift3,
    float* __restrict__ out) {
    __shared__ __align__(16) float xs[CIN][36];
    __shared__ float wrl[COUT * 33];
    int t = threadIdx.x;
    int bn = blockIdx.x;
    int b = bn >> 10, n = bn & (NN - 1);
    {
        int sst = t & 31, cinb = t >> 5;            // bank 2-way
#pragma unroll
        for (int i = 0; i < 4; i++) {
            int cin = cinb + 8 * i;
            xs[cin][sst] = x[(((size_t)b * CIN + cin) * NN + n) * SS + sst];
        }
    }
#pragma unroll
    for (int i = 0; i < 2; i++) {
        int lin = (i * 256 + t) * 4;                // rows of 32
        int cw = lin >> 5, c0 = lin & 31;
        float4 v = *(const float4*)(Wres + lin);
        float* dst = &wrl[cw * 33 + c0];
        dst[0] = v.x; dst[1] = v.y; dst[2] = v.z; dst[3] = v.w;
    }
    __syncthreads();
    int cout = t >> 2, s0 = (t & 3) * 8;
    float res[8];
    float bb = bres[cout];
#pragma unroll
    for (int j = 0; j < 8; j++) res[j] = bb;
    const float* wrow = &wrl[cout * 33];
#pragma unroll 4
    for (int cin = 0; cin < CIN; cin++) {
        float w = wrow[cin];
        float4 xa = *(const float4*)&xs[cin][s0];
        float4 xb = *(const float4*)&xs[cin][s0 + 4];
        res[0] += xa.x * w; res[1] += xa.y * w; res[2] += xa.z * w; res[3] += xa.w * w;
        res[4] += xb.x * w; res[5] += xb.y * w; res[6] += xb.z * w; res[7] += xb.w * w;
    }
    const float* hp = h2_pre + (size_t)bn * COUT * SS + cout * SS + s0;
    float4 h0 = *(const float4*)hp, h1 = *(const float4*)(hp + 4);
    float h2[8] = {h0.x, h0.y, h0.z, h0.w, h1.x, h1.y, h1.z, h1.w};
    float sc = scale3[cout], sh = shift3[cout];
    float o[8];
#pragma unroll
    for (int j = 0; j < 8; j++) {
        float hv = fmaxf(sc * h2[j] + sh, 0.f);
        o[j] = fmaxf(hv + res[j], 0.f);
    }
    float* op = out + (((size_t)b * COUT + cout) * NN + n) * SS + s0;
    float4 o0 = {o[0], o[1], o[2], o[3]}, o1 = {o[4], o[5], o[6], o[7]};
    *(float4*)op = o0; *(float4*)(op + 4) = o1;
}

// ---------- host ----------
extern "C" void kernel_launch(void* const* d_in, const int* in_sizes, int n_in,
                              void* d_out, int out_size, void* d_ws, size_t ws_size,
                              hipStream_t stream) {
    const float* x    = (const float*)d_in[0];
    const int*   ei   = (const int*)  d_in[1];
    const float* W1   = (const float*)d_in[2];
    const float* b1   = (const float*)d_in[3];
    const float* g1   = (const float*)d_in[4];
    const float* be1  = (const float*)d_in[5];
    const float* Wg   = (const float*)d_in[6];
    const float* bg   = (const float*)d_in[7];
    const float* gs   = (const float*)d_in[8];
    const float* bes  = (const float*)d_in[9];
    const float* W2   = (const float*)d_in[10];
    const float* b2   = (const float*)d_in[11];
    const float* g2   = (const float*)d_in[12];
    const float* be2  = (const float*)d_in[13];
    const float* Wres = (const float*)d_in[14];
    const float* bres = (const float*)d_in[15];
    float* out = (float*)d_out;
    int E = in_sizes[1] / 2;

    char* ws = (char*)d_ws;
    // zeroed region: [0, 73728)
    int*   deg    = (int*)  (ws + 0);            // 4096 B
    int*   cursor = (int*)  (ws + 4096);         // 4096 B
    float* sum2   = (float*)(ws + 8192);         // 32768 B
    float* ssq2   = (float*)(ws + 40960);        // 32768 B -> ends 73728
    int*   row_ptr= (int*)  (ws + 73728);        // 4100 B
    int*   flag   = (int*)  (ws + 77888);        // 4 B
    float* dinv   = (float*)(ws + 78080);        // 4096 B
    float* scale1 = (float*)(ws + 82176);        // 256 B each
    float* shift1 = (float*)(ws + 82432);
    float* scale3 = (float*)(ws + 82688);
    float* shift3 = (float*)(ws + 82944);
    float* scale2 = (float*)(ws + 83200);        // 32768 B
    float* shift2 = (float*)(ws + 115968);       // 32768 B -> 148736
    float* psum   = (float*)(ws + 148736);       // 131072 B (64 ch x 512 slots)
    float* pss    = (float*)(ws + 279808);       // 131072 B -> 410880
    int2*  edata  = (int2*) (ws + 410880);       // 8*E = 131072 B -> 541952
    float* bigA   = (float*)(ws + 542720);       // 33.55 MB: hw, then h2_pre
    // d_out doubles as scratch: h_pre (conv1 out), then agg (gcn out).
    float* h_pre  = out;
    float* agg    = out;

    hipMemsetAsync(ws, 0, 73728, stream);
    detect_kernel<<<1, 64, 0, stream>>>(ei, flag);
    int egrid = (E + 255) / 256;
    deg_count_kernel<<<egrid, 256, 0, stream>>>(ei, E, flag, deg);
    scan_kernel<<<1, NN, 0, stream>>>(deg, row_ptr, dinv);
    csr_fill_kernel<<<egrid, 256, 0, stream>>>(ei, E, flag, row_ptr, cursor, dinv, edata);

    conv1_kernel<<<512, 512, 0, stream>>>(x, W1, b1, h_pre, psum, pss);
    bn_reduce_kernel<<<64, 256, 0, stream>>>(psum, pss, g1, be1, scale1, shift1,
                                             1.f / (B_ * NN * SS), 512, 512);
    bn1_gemm_kernel<<<1024, 256, 0, stream>>>(h_pre, scale1, shift1, Wg, bigA);
    gcn_kernel<<<B_ * SS * (NN / 32), 256, 0, stream>>>(bigA, row_ptr, edata, dinv, bg, agg,
                                                        sum2, ssq2);
    bn2_finalize_kernel<<<32, 256, 0, stream>>>(sum2, ssq2, gs, bes, scale2, shift2);
    conv2_kernel<<<512, 512, 0, stream>>>(agg, scale2, shift2, W2, b2, bigA, psum, pss);
    bn_reduce_kernel<<<64, 256, 0, stream>>>(psum, pss, g2, be2, scale3, shift3,
                                             1.f / (B_ * NN * SS), 512, 512);
    final_kernel<<<B_ * NN, 256, 0, stream>>>(x, Wres, bres, bigA, scale3, shift3, out);
}